// Round 2
// baseline (106.245 us; speedup 1.0000x reference)
//
#include <hip/hip_runtime.h>
#include <math.h>

#define HW 512
#define CH 64
#define KSZ 576              // C*K*K = 64*9
#define WS_ACT 0
#define WS_SCALE 576
#define WS_RQ 1152
#define WS_SX 1728
#define XF_OFF (64 * KSZ)    // wq elements = 36864, xf follows

__device__ __forceinline__ void atomic_max_f(float* addr, float v) {
  // values are non-negative -> positive-float ordering == int ordering
  atomicMax(reinterpret_cast<int*>(addr), __float_as_int(v));
}

// ---------------------------------------------------------------------------
// Kernel 1: act_scale[c*9 + kh*3 + kw] = max |input[c, h, w]| over
//   h in Rh(kh), w in Cw(kw) with Rh(0)=[0,510], Rh(1)=[0,511], Rh(2)=[1,511]
// (same for Cw). Interior pixels belong to all 9 regions -> fast path.
// ---------------------------------------------------------------------------
__global__ __launch_bounds__(256) void k_actscale(const float* __restrict__ in,
                                                  float* __restrict__ ws) {
  const int c = blockIdx.x >> 4;          // 64 channels
  const int h0 = (blockIdx.x & 15) * 32;  // 16 row-chunks of 32 rows
  const int t = threadIdx.x;
  const float4* base =
      reinterpret_cast<const float4*>(in + (size_t)c * HW * HW + (size_t)h0 * HW);

  float m9[3][3];
#pragma unroll
  for (int a = 0; a < 3; ++a)
#pragma unroll
    for (int b = 0; b < 3; ++b) m9[a][b] = 0.f;
  float mi = 0.f;

#pragma unroll
  for (int k = 0; k < 16; ++k) {          // 32 rows * 128 float4 / 256 thr
    const int idx4 = k * 256 + t;
    const int row = idx4 >> 7;
    const int col4 = idx4 & 127;
    const float4 v = base[idx4];
    const int h = h0 + row;
    const float av0 = fabsf(v.x), av1 = fabsf(v.y), av2 = fabsf(v.z), av3 = fabsf(v.w);
    const bool interior = (h >= 1) && (h <= 510) && (col4 >= 1) && (col4 <= 126);
    if (interior) {
      mi = fmaxf(mi, fmaxf(fmaxf(av0, av1), fmaxf(av2, av3)));
    } else {
      const float av[4] = {av0, av1, av2, av3};
      const bool hok[3] = {h <= 510, true, h >= 1};
#pragma unroll
      for (int i = 0; i < 4; ++i) {
        const int w = col4 * 4 + i;
        const bool wok[3] = {w <= 510, true, w >= 1};
#pragma unroll
        for (int a = 0; a < 3; ++a)
#pragma unroll
          for (int b = 0; b < 3; ++b)
            if (hok[a] && wok[b]) m9[a][b] = fmaxf(m9[a][b], av[i]);
      }
    }
  }
#pragma unroll
  for (int a = 0; a < 3; ++a)
#pragma unroll
    for (int b = 0; b < 3; ++b) m9[a][b] = fmaxf(m9[a][b], mi);

  // 64-lane butterfly reduce, then one atomic per wave per cell
#pragma unroll
  for (int m = 32; m >= 1; m >>= 1) {
#pragma unroll
    for (int a = 0; a < 3; ++a)
#pragma unroll
      for (int b = 0; b < 3; ++b) m9[a][b] = fmaxf(m9[a][b], __shfl_xor(m9[a][b], m));
  }
  if ((t & 63) == 0) {
#pragma unroll
    for (int a = 0; a < 3; ++a)
#pragma unroll
      for (int b = 0; b < 3; ++b)
        atomic_max_f(&ws[WS_ACT + c * 9 + a * 3 + b], m9[a][b]);
  }
}

// ---------------------------------------------------------------------------
// Kernel 2: per-column w_scale, SmoothQuant scale, global amaxes, s_x/s_w,
// rq[j] = 1/(scale[j]*s_x), and the fused wq output (Cout,K,K,C).
// Single block of 576 threads (one per column j = c*9 + kh*3 + kw).
// ---------------------------------------------------------------------------
__global__ __launch_bounds__(576) void k_scale_wq(const float* __restrict__ wgt,
                                                  float* __restrict__ ws,
                                                  float* __restrict__ out) {
  __shared__ float rx9[9], rw9[9];
  __shared__ float s_sx, s_sw;
  const int j = threadIdx.x;

  float wmax = 0.f;
  for (int co = 0; co < 64; ++co) wmax = fmaxf(wmax, fabsf(wgt[co * KSZ + j]));

  const float act = ws[WS_ACT + j];
  float scale = sqrtf(act) / sqrtf(wmax);   // alpha = 0.5
  if (scale == 0.f) scale = 1.f;

  // column maxima of |x/scale| and |w*scale| (monotone under positive scale)
  float rx = act / scale;
  float rw = wmax * scale;
#pragma unroll
  for (int m = 32; m >= 1; m >>= 1) {
    rx = fmaxf(rx, __shfl_xor(rx, m));
    rw = fmaxf(rw, __shfl_xor(rw, m));
  }
  if ((j & 63) == 0) { rx9[j >> 6] = rx; rw9[j >> 6] = rw; }
  __syncthreads();
  if (j == 0) {
    float mx = rx9[0], mw = rw9[0];
    for (int i = 1; i < 9; ++i) { mx = fmaxf(mx, rx9[i]); mw = fmaxf(mw, rw9[i]); }
    s_sx = (mx > 0.f) ? (mx / 127.f) : 1.f;
    s_sw = (mw > 0.f) ? (mw / 127.f) : 1.f;
    ws[WS_SX] = s_sx;
  }
  __syncthreads();
  const float sx = s_sx, sw = s_sw;

  ws[WS_SCALE + j] = scale;
  ws[WS_RQ + j] = 1.f / (scale * sx);

  // wq[cout, kh, kw, c] = fq(w[cout, c, kh, kw] * scale[j]; s_w)
  const int c = j / 9;
  const int r = j - c * 9;                 // kh*3+kw
  const int obase = r * 64 + c;
  for (int co = 0; co < 64; ++co) {
    float u = (wgt[co * KSZ + j] * scale) / sw;
    u = fminf(fmaxf(u, -127.f), 127.f);
    out[co * KSZ + obase] = rintf(u) * sw;
  }
}

// ---------------------------------------------------------------------------
// Kernel 3: xf[h, w, c] = s_x * sum_{valid kh,kw} rint(clamp(v * rq[c,kh,kw]))
// Per-pixel local. Tile: one h row x 64 w x 64 c per block; LDS transpose so
// input reads (NCHW) and output writes (NHWC) are both coalesced.
// ---------------------------------------------------------------------------
__global__ __launch_bounds__(256) void k_main(const float* __restrict__ in,
                                              const float* __restrict__ ws,
                                              float* __restrict__ out) {
  __shared__ float rq_s[KSZ];
  __shared__ float sx_s;
  __shared__ float ldsT[64][68];           // [w_local][c], padded (2-way max)
  const int t = threadIdx.x;
  const int h = blockIdx.x >> 3;
  const int w0 = (blockIdx.x & 7) * 64;

  for (int i = t; i < KSZ; i += 256) rq_s[i] = ws[WS_RQ + i];
  if (t == 0) sx_s = ws[WS_SX];
  __syncthreads();

  const int c = t >> 2;                    // 4 threads per channel row
  const int fi = t & 3;
  float rq[9];
#pragma unroll
  for (int j = 0; j < 9; ++j) rq[j] = rq_s[c * 9 + j];
  const float sx = sx_s;
  const bool hok0 = (h <= 510);            // kh=0 valid
  const bool hok2 = (h >= 1);              // kh=2 valid

  const float4* ibase =
      reinterpret_cast<const float4*>(in + (size_t)c * HW * HW + (size_t)h * HW + w0);
#pragma unroll
  for (int k = 0; k < 4; ++k) {
    const int w4 = fi + 4 * k;
    const float4 v = ibase[w4];
    const float vv[4] = {v.x, v.y, v.z, v.w};
#pragma unroll
    for (int i = 0; i < 4; ++i) {
      const int wl = w4 * 4 + i;
      const int w = w0 + wl;
      const bool wok0 = (w <= 510);        // kw=0 valid
      const bool wok2 = (w >= 1);          // kw=2 valid
      const bool ok[9] = {hok0 && wok0, hok0, hok0 && wok2,
                          wok0,         true, wok2,
                          hok2 && wok0, hok2, hok2 && wok2};
      float qs = 0.f;
#pragma unroll
      for (int jj = 0; jj < 9; ++jj) {
        float u = vv[i] * rq[jj];
        u = fminf(fmaxf(u, -127.f), 127.f);
        const float q = rintf(u);
        qs += ok[jj] ? q : 0.f;            // integer-valued: sum is exact
      }
      ldsT[wl][c] = qs * sx;
    }
  }
  __syncthreads();

  float4* obase =
      reinterpret_cast<float4*>(out + XF_OFF + ((size_t)h * HW + w0) * 64);
#pragma unroll
  for (int k = 0; k < 4; ++k) {
    const int idx4 = k * 256 + t;          // linear over [w_local][c] tile
    const int lw = idx4 >> 4;
    const int lc4 = idx4 & 15;
    obase[idx4] = *reinterpret_cast<const float4*>(&ldsT[lw][lc4 * 4]);
  }
}

extern "C" void kernel_launch(void* const* d_in, const int* in_sizes, int n_in,
                              void* d_out, int out_size, void* d_ws, size_t ws_size,
                              hipStream_t stream) {
  (void)in_sizes; (void)n_in; (void)out_size; (void)ws_size;
  const float* in = reinterpret_cast<const float*>(d_in[0]);   // (1,64,512,512)
  const float* wgt = reinterpret_cast<const float*>(d_in[1]);  // (64,64,3,3)
  float* out = reinterpret_cast<float*>(d_out);                // wq | xf
  float* ws = reinterpret_cast<float*>(d_ws);

  (void)hipMemsetAsync(d_ws, 0, KSZ * sizeof(float), stream);  // act_scale = 0
  k_actscale<<<dim3(64 * 16), dim3(256), 0, stream>>>(in, ws);
  k_scale_wq<<<dim3(1), dim3(576), 0, stream>>>(wgt, ws, out);
  k_main<<<dim3(512 * 8), dim3(256), 0, stream>>>(in, ws, out);
}

// Round 3
// 70.707 us; speedup vs baseline: 1.5026x; 1.5026x over previous
//
#include <hip/hip_runtime.h>
#include <math.h>

#define HW 512
#define KSZ 576                  // C*K*K = 64*9
#define NCHUNK 32
#define WS_PART 0                // 32*576 per-chunk act partial maxes
#define WS_RQ   (NCHUNK * KSZ)   // 576 floats
#define WS_SX   (WS_RQ + KSZ)    // 1 float
#define XF_OFF  (64 * KSZ)       // wq = 36864 elements, xf follows

// ---------------------------------------------------------------------------
// Kernel 1: per-(channel, 16-row chunk) partial maxima of |input| for the 9
// (kh,kw) regions. w-variants: All = w in [0,511], NoL = w<=510, No0 = w>=1.
// Row-variants handled only for chunks 0 (h=0) / 31 (h=511).
// ---------------------------------------------------------------------------
__global__ __launch_bounds__(256) void k_actscale(const float* __restrict__ in,
                                                  float* __restrict__ ws) {
  const int c = blockIdx.x >> 5;
  const int chunk = blockIdx.x & 31;
  const int t = threadIdx.x;
  const float4* base = reinterpret_cast<const float4*>(
      in + (size_t)c * HW * HW + (size_t)(chunk << 4) * HW);

  float4 v[8];
#pragma unroll
  for (int k = 0; k < 8; ++k) v[k] = base[k * 256 + t];   // 8 loads in flight

  const int col4 = t & 127;     // fixed per thread: w-border lanes are static
  const int tb = t >> 7;        // local row parity
  float aAll = 0.f, aNo0 = 0.f, aNoL = 0.f;   // over all rows of chunk
  float bAll = 0.f, bNo0 = 0.f, bNoL = 0.f;   // excluding chunk's border row
#pragma unroll
  for (int k = 0; k < 8; ++k) {
    const float e0 = fabsf(v[k].x), e1 = fabsf(v[k].y),
                e2 = fabsf(v[k].z), e3 = fabsf(v[k].w);
    const float m4 = fmaxf(fmaxf(e0, e1), fmaxf(e2, e3));
    const float vNo0 = (col4 == 0)   ? fmaxf(fmaxf(e1, e2), e3) : m4; // excl w=0
    const float vNoL = (col4 == 127) ? fmaxf(fmaxf(e0, e1), e2) : m4; // excl w=511
    aAll = fmaxf(aAll, m4); aNo0 = fmaxf(aNo0, vNo0); aNoL = fmaxf(aNoL, vNoL);
    const int lrow = 2 * k + tb;
    const bool keep = !((chunk == 0 && lrow == 0) || (chunk == 31 && lrow == 15));
    if (keep) {
      bAll = fmaxf(bAll, m4); bNo0 = fmaxf(bNo0, vNo0); bNoL = fmaxf(bNoL, vNoL);
    }
  }
#pragma unroll
  for (int m = 32; m >= 1; m >>= 1) {
    aAll = fmaxf(aAll, __shfl_xor(aAll, m));
    aNo0 = fmaxf(aNo0, __shfl_xor(aNo0, m));
    aNoL = fmaxf(aNoL, __shfl_xor(aNoL, m));
    bAll = fmaxf(bAll, __shfl_xor(bAll, m));
    bNo0 = fmaxf(bNo0, __shfl_xor(bNo0, m));
    bNoL = fmaxf(bNoL, __shfl_xor(bNoL, m));
  }
  __shared__ float red[4][6];
  if ((t & 63) == 0) {
    const int wv = t >> 6;
    red[wv][0] = aAll; red[wv][1] = aNo0; red[wv][2] = aNoL;
    red[wv][3] = bAll; red[wv][4] = bNo0; red[wv][5] = bNoL;
  }
  __syncthreads();
  if (t == 0) {
    float r[6];
#pragma unroll
    for (int i = 0; i < 6; ++i)
      r[i] = fmaxf(fmaxf(red[0][i], red[1][i]), fmaxf(red[2][i], red[3][i]));
    // kw mapping: kw=0 -> w<=510 (NoL), kw=1 -> All, kw=2 -> w>=1 (No0)
    const float Aw[3] = {r[2], r[0], r[1]};
    const float Bw[3] = {r[5], r[3], r[4]};
    float* p = ws + WS_PART + chunk * KSZ + c * 9;
#pragma unroll
    for (int b = 0; b < 3; ++b) {
      p[0 * 3 + b] = (chunk == 31) ? Bw[b] : Aw[b];  // kh=0: h<=510
      p[1 * 3 + b] = Aw[b];                          // kh=1: all h
      p[2 * 3 + b] = (chunk == 0) ? Bw[b] : Aw[b];   // kh=2: h>=1
    }
  }
}

// ---------------------------------------------------------------------------
// Kernel 2: reduce partials -> act_scale; SmoothQuant scale; global amaxes;
// rq[j] = 1/(scale[j]*s_x); fused wq output (Cout,K,K,C). One 576-thread block.
// ---------------------------------------------------------------------------
__global__ __launch_bounds__(576) void k_scale_wq(const float* __restrict__ wgt,
                                                  float* __restrict__ ws,
                                                  float* __restrict__ out) {
  __shared__ float rx9[9], rw9[9];
  __shared__ float s_sx, s_sw;
  const int j = threadIdx.x;

  float act = 0.f;
#pragma unroll
  for (int ch = 0; ch < NCHUNK; ++ch)
    act = fmaxf(act, ws[WS_PART + ch * KSZ + j]);

  float wmax = 0.f;
#pragma unroll 8
  for (int co = 0; co < 64; ++co) wmax = fmaxf(wmax, fabsf(wgt[co * KSZ + j]));

  float scale = sqrtf(act) / sqrtf(wmax);   // alpha = 0.5
  if (scale == 0.f) scale = 1.f;

  float rx = act / scale;    // column max of |x/scale| (monotone in scale)
  float rw = wmax * scale;
#pragma unroll
  for (int m = 32; m >= 1; m >>= 1) {
    rx = fmaxf(rx, __shfl_xor(rx, m));
    rw = fmaxf(rw, __shfl_xor(rw, m));
  }
  if ((j & 63) == 0) { rx9[j >> 6] = rx; rw9[j >> 6] = rw; }
  __syncthreads();
  if (j == 0) {
    float mx = rx9[0], mw = rw9[0];
    for (int i = 1; i < 9; ++i) { mx = fmaxf(mx, rx9[i]); mw = fmaxf(mw, rw9[i]); }
    s_sx = (mx > 0.f) ? (mx / 127.f) : 1.f;
    s_sw = (mw > 0.f) ? (mw / 127.f) : 1.f;
    ws[WS_SX] = s_sx;
  }
  __syncthreads();
  const float sx = s_sx, sw = s_sw;

  ws[WS_RQ + j] = 1.f / (scale * sx);

  // wq[cout, kh, kw, c] = fq(w[cout, c, kh, kw] * scale[j]; s_w)
  const int c = j / 9;
  const int r = j - c * 9;
  const int obase = r * 64 + c;
#pragma unroll 8
  for (int co = 0; co < 64; ++co) {
    float u = (wgt[co * KSZ + j] * scale) / sw;
    u = fminf(fmaxf(u, -127.f), 127.f);
    out[co * KSZ + obase] = rintf(u) * sw;
  }
}

// ---------------------------------------------------------------------------
// Kernel 3: xf[h,w,c] = s_x * sum_{valid kh,kw} rint(clamp(v*rq[c,kh,kw])).
// Interior fast path: all 9 terms valid and provably |u|<=127(1+eps) -> no
// clamp, no mask. Border lanes (h or w in {0,511}) take masked slow path.
// 512 threads = 2 rows x 64 w x 64 c; LDS transpose NCHW->NHWC.
// ---------------------------------------------------------------------------
__global__ __launch_bounds__(512) void k_main(const float* __restrict__ in,
                                              const float* __restrict__ ws,
                                              float* __restrict__ out) {
  __shared__ float rq_s[KSZ];
  __shared__ float sx_s;
  __shared__ float ldsT[2][64][68];   // [row][w_local][c], pad 68 (2-way max)
  const int t = threadIdx.x;
  const int h0 = (blockIdx.x >> 3) << 1;
  const int w0 = (blockIdx.x & 7) << 6;

  rq_s[t < KSZ ? t : 0] = ws[WS_RQ + (t < KSZ ? t : 0)];
  if (t < KSZ - 512) rq_s[512 + t] = ws[WS_RQ + 512 + t];
  if (t == 0) sx_s = ws[WS_SX];
  __syncthreads();

  const int hl = t >> 8;
  const int h = h0 + hl;
  const int tt = t & 255;
  const int c = tt >> 2;
  const int fi = tt & 3;
  float rq[9];
#pragma unroll
  for (int j = 0; j < 9; ++j) rq[j] = rq_s[c * 9 + j];
  const float sx = sx_s;

  const float4* ibase = reinterpret_cast<const float4*>(
      in + (size_t)c * HW * HW + (size_t)h * HW + w0);
  float4 v[4];
#pragma unroll
  for (int k = 0; k < 4; ++k) v[k] = ibase[fi + 4 * k];   // 4 loads in flight

  const bool hb = (h == 0) || (h == 511);
#pragma unroll
  for (int k = 0; k < 4; ++k) {
    const float vv[4] = {v[k].x, v[k].y, v[k].z, v[k].w};
#pragma unroll
    for (int i = 0; i < 4; ++i) {
      const int wl = (fi + 4 * k) * 4 + i;
      const int w = w0 + wl;
      const float x = vv[i];
      float qs = 0.f;
#pragma unroll
      for (int jj = 0; jj < 9; ++jj) qs += rintf(x * rq[jj]);  // exact int sum
      if (hb || (w == 0) || (w == 511)) {                      // rare fix-up
        const bool hok0 = (h <= 510), hok2 = (h >= 1);
        const bool wok0 = (w <= 510), wok2 = (w >= 1);
        const bool ok[9] = {hok0 && wok0, hok0, hok0 && wok2,
                            wok0,         true, wok2,
                            hok2 && wok0, hok2, hok2 && wok2};
        qs = 0.f;
#pragma unroll
        for (int jj = 0; jj < 9; ++jj) {
          const float u = fminf(fmaxf(x * rq[jj], -127.f), 127.f);
          qs += ok[jj] ? rintf(u) : 0.f;
        }
      }
      ldsT[hl][wl][c] = qs * sx;
    }
  }
  __syncthreads();

#pragma unroll
  for (int k = 0; k < 4; ++k) {
    const int idx4 = k * 512 + t;
    const int half = idx4 >> 10;
    const int idx = idx4 & 1023;
    const int lw = idx >> 4;
    const int lc4 = idx & 15;
    float4* obase = reinterpret_cast<float4*>(
        out + XF_OFF + ((size_t)(h0 + half) * HW + w0) * 64);
    obase[idx] = *reinterpret_cast<const float4*>(&ldsT[half][lw][lc4 * 4]);
  }
}

extern "C" void kernel_launch(void* const* d_in, const int* in_sizes, int n_in,
                              void* d_out, int out_size, void* d_ws, size_t ws_size,
                              hipStream_t stream) {
  (void)in_sizes; (void)n_in; (void)out_size; (void)ws_size;
  const float* in = reinterpret_cast<const float*>(d_in[0]);   // (1,64,512,512)
  const float* wgt = reinterpret_cast<const float*>(d_in[1]);  // (64,64,3,3)
  float* out = reinterpret_cast<float*>(d_out);                // wq | xf
  float* ws = reinterpret_cast<float*>(d_ws);

  k_actscale<<<dim3(64 * 32), dim3(256), 0, stream>>>(in, ws);
  k_scale_wq<<<dim3(1), dim3(576), 0, stream>>>(wgt, ws, out);
  k_main<<<dim3(256 * 8), dim3(512), 0, stream>>>(in, ws, out);
}

// Round 5
// 68.257 us; speedup vs baseline: 1.5565x; 1.0359x over previous
//
#include <hip/hip_runtime.h>
#include <math.h>

#define HW 512
#define KSZ 576                  // C*K*K = 64*9
#define WS_ACT 0                 // 576 floats (atomic-max accumulators)
#define WS_WMAX 576              // 576 floats
#define XF_OFF (64 * KSZ)        // wq = 36864 elements, xf follows

__device__ __forceinline__ void atomic_max_f(float* addr, float v) {
  // values are non-negative -> positive-float ordering == int ordering
  atomicMax(reinterpret_cast<int*>(addr), __float_as_int(v));
}

// ---------------------------------------------------------------------------
// Kernel 1 (2048 blocks): per-(channel, 16-row chunk) maxima of |input| for
// the 9 (kh,kw) validity regions, atomic-maxed into ws[WS_ACT + c*9 + r].
// Blocks 2048..2050: wmax[j] = max_co |wgt[co,j]| (runs concurrently).
// ---------------------------------------------------------------------------
__global__ __launch_bounds__(256) void k_pass1(const float* __restrict__ in,
                                               const float* __restrict__ wgt,
                                               float* __restrict__ ws) {
  const int t = threadIdx.x;
  if (blockIdx.x >= 2048) {                  // wmax tail blocks
    const int j = (blockIdx.x - 2048) * 256 + t;
    if (j < KSZ) {
      float wm = 0.f;
#pragma unroll 16
      for (int co = 0; co < 64; ++co) wm = fmaxf(wm, fabsf(wgt[co * KSZ + j]));
      ws[WS_WMAX + j] = wm;
    }
    return;
  }
  const int c = blockIdx.x >> 5;
  const int chunk = blockIdx.x & 31;
  const float4* base = reinterpret_cast<const float4*>(
      in + (size_t)c * HW * HW + (size_t)(chunk << 4) * HW);

  float4 v[8];
#pragma unroll
  for (int k = 0; k < 8; ++k) v[k] = base[k * 256 + t];   // 8 loads in flight

  const int col4 = t & 127;     // w-border lanes are static per thread
  const int tb = t >> 7;
  float aAll = 0.f, aNo0 = 0.f, aNoL = 0.f;   // all rows of chunk
  float bAll = 0.f, bNo0 = 0.f, bNoL = 0.f;   // excluding chunk's border row
#pragma unroll
  for (int k = 0; k < 8; ++k) {
    const float e0 = fabsf(v[k].x), e1 = fabsf(v[k].y),
                e2 = fabsf(v[k].z), e3 = fabsf(v[k].w);
    const float m4 = fmaxf(fmaxf(e0, e1), fmaxf(e2, e3));
    const float vNo0 = (col4 == 0)   ? fmaxf(fmaxf(e1, e2), e3) : m4; // excl w=0
    const float vNoL = (col4 == 127) ? fmaxf(fmaxf(e0, e1), e2) : m4; // excl w=511
    aAll = fmaxf(aAll, m4); aNo0 = fmaxf(aNo0, vNo0); aNoL = fmaxf(aNoL, vNoL);
    const int lrow = 2 * k + tb;
    const bool keep = !((chunk == 0 && lrow == 0) || (chunk == 31 && lrow == 15));
    if (keep) {
      bAll = fmaxf(bAll, m4); bNo0 = fmaxf(bNo0, vNo0); bNoL = fmaxf(bNoL, vNoL);
    }
  }
#pragma unroll
  for (int m = 32; m >= 1; m >>= 1) {
    aAll = fmaxf(aAll, __shfl_xor(aAll, m));
    aNo0 = fmaxf(aNo0, __shfl_xor(aNo0, m));
    aNoL = fmaxf(aNoL, __shfl_xor(aNoL, m));
    bAll = fmaxf(bAll, __shfl_xor(bAll, m));
    bNo0 = fmaxf(bNo0, __shfl_xor(bNo0, m));
    bNoL = fmaxf(bNoL, __shfl_xor(bNoL, m));
  }
  __shared__ float red[4][6];
  if ((t & 63) == 0) {
    const int wv = t >> 6;
    red[wv][0] = aAll; red[wv][1] = aNo0; red[wv][2] = aNoL;
    red[wv][3] = bAll; red[wv][4] = bNo0; red[wv][5] = bNoL;
  }
  __syncthreads();
  if (t == 0) {
    float r[6];
#pragma unroll
    for (int i = 0; i < 6; ++i)
      r[i] = fmaxf(fmaxf(red[0][i], red[1][i]), fmaxf(red[2][i], red[3][i]));
    // kw mapping: kw=0 -> w<=510 (NoL), kw=1 -> All, kw=2 -> w>=1 (No0)
    const float Aw[3] = {r[2], r[0], r[1]};
    const float Bw[3] = {r[5], r[3], r[4]};
    float* p = ws + WS_ACT + c * 9;
#pragma unroll
    for (int b = 0; b < 3; ++b) {
      atomic_max_f(&p[0 * 3 + b], (chunk == 31) ? Bw[b] : Aw[b]);  // kh=0: h<=510
      atomic_max_f(&p[1 * 3 + b], Aw[b]);                          // kh=1
      atomic_max_f(&p[2 * 3 + b], (chunk == 0) ? Bw[b] : Aw[b]);   // kh=2: h>=1
    }
  }
}

// ---------------------------------------------------------------------------
// Kernel 2 (1024 blocks x 512 thr): each block re-derives scale/sx/sw/rq from
// ws (1152 floats, L2-hit; identical FP ops -> deterministic). Blocks 0..63
// write wq row co=blockIdx (looped over 2 reps to cover all 576 columns with
// 512 threads). Then all blocks: 4-row x 64w x 64c quantize tile, interior
// no-clamp fast path, LDS transpose NCHW->NHWC.
// ---------------------------------------------------------------------------
__global__ __launch_bounds__(512, 4) void k_fused(const float* __restrict__ in,
                                                  const float* __restrict__ wgt,
                                                  const float* __restrict__ ws,
                                                  float* __restrict__ out) {
  __shared__ float scale_s[KSZ];
  __shared__ float rq_s[KSZ];
  __shared__ float ldsT[4][64][68];   // [row][w_local][c], pad 68
  __shared__ float wred[8][2];
  __shared__ float s_sx, s_sw;
  const int t = threadIdx.x;

  // ---- scales (redundant per block, tiny) ----
  float rxm = 0.f, rwm = 0.f;
#pragma unroll
  for (int rep = 0; rep < 2; ++rep) {
    const int j = t + rep * 512;
    if (j < KSZ) {
      const float act = ws[WS_ACT + j];
      const float wm = ws[WS_WMAX + j];
      float scale = sqrtf(act) / sqrtf(wm);   // alpha = 0.5
      if (scale == 0.f) scale = 1.f;
      scale_s[j] = scale;
      rxm = fmaxf(rxm, act / scale);
      rwm = fmaxf(rwm, wm * scale);
    }
  }
#pragma unroll
  for (int m = 32; m >= 1; m >>= 1) {
    rxm = fmaxf(rxm, __shfl_xor(rxm, m));
    rwm = fmaxf(rwm, __shfl_xor(rwm, m));
  }
  if ((t & 63) == 0) { wred[t >> 6][0] = rxm; wred[t >> 6][1] = rwm; }
  __syncthreads();
  if (t == 0) {
    float mx = wred[0][0], mw = wred[0][1];
    for (int i = 1; i < 8; ++i) { mx = fmaxf(mx, wred[i][0]); mw = fmaxf(mw, wred[i][1]); }
    s_sx = (mx > 0.f) ? (mx / 127.f) : 1.f;
    s_sw = (mw > 0.f) ? (mw / 127.f) : 1.f;
  }
  __syncthreads();
  const float sx = s_sx, sw = s_sw;
#pragma unroll
  for (int rep = 0; rep < 2; ++rep) {
    const int j = t + rep * 512;
    if (j < KSZ) rq_s[j] = 1.f / (scale_s[j] * sx);
  }
  __syncthreads();

  // ---- wq epilogue: blocks 0..63 each write one cout row (2 reps: 512 thr,
  //      576 columns — rep loop REQUIRED, t alone misses j>=512) ----
  if (blockIdx.x < 64) {
    const int co = blockIdx.x;
#pragma unroll
    for (int rep = 0; rep < 2; ++rep) {
      const int j = t + rep * 512;
      if (j < KSZ) {
        const int c = j / 9;
        const int r = j - c * 9;
        float u = (wgt[co * KSZ + j] * scale_s[j]) / sw;
        u = fminf(fmaxf(u, -127.f), 127.f);
        out[co * KSZ + r * 64 + c] = rintf(u) * sw;
      }
    }
  }

  // ---- main tile ----
  const int h0 = (blockIdx.x >> 3) << 2;   // 128 h-blocks * 4 rows
  const int w0 = (blockIdx.x & 7) << 6;
  const int c = t >> 3;                    // 8 threads per channel
  const int fi = t & 7;
  float rq[9];
#pragma unroll
  for (int jq = 0; jq < 9; ++jq) rq[jq] = rq_s[c * 9 + jq];

  const float4* ibase = reinterpret_cast<const float4*>(
      in + (size_t)c * HW * HW + (size_t)h0 * HW + w0);
  float4 v[8];
#pragma unroll
  for (int row = 0; row < 4; ++row) {      // 8 loads in flight
    v[row * 2 + 0] = ibase[row * 128 + fi];
    v[row * 2 + 1] = ibase[row * 128 + fi + 8];
  }

#pragma unroll
  for (int row = 0; row < 4; ++row) {
    const int h = h0 + row;
    const bool hb = (h == 0) || (h == 511);
#pragma unroll
    for (int q = 0; q < 2; ++q) {
      const float4 v4 = v[row * 2 + q];
      const int f4 = fi + 8 * q;
      const float vv[4] = {v4.x, v4.y, v4.z, v4.w};
#pragma unroll
      for (int i = 0; i < 4; ++i) {
        const int wl = f4 * 4 + i;
        const int w = w0 + wl;
        const float x = vv[i];
        float qs = 0.f;
#pragma unroll
        for (int jj = 0; jj < 9; ++jj) qs += rintf(x * rq[jj]);  // exact int sum
        if (hb || (w == 0) || (w == 511)) {                      // rare fix-up
          const bool hok0 = (h <= 510), hok2 = (h >= 1);
          const bool wok0 = (w <= 510), wok2 = (w >= 1);
          const bool ok[9] = {hok0 && wok0, hok0, hok0 && wok2,
                              wok0,         true, wok2,
                              hok2 && wok0, hok2, hok2 && wok2};
          qs = 0.f;
#pragma unroll
          for (int jj = 0; jj < 9; ++jj) {
            const float u = fminf(fmaxf(x * rq[jj], -127.f), 127.f);
            qs += ok[jj] ? rintf(u) : 0.f;
          }
        }
        ldsT[row][wl][c] = qs * sx;
      }
    }
  }
  __syncthreads();

#pragma unroll
  for (int k = 0; k < 8; ++k) {
    const int idx4 = k * 512 + t;
    const int row = idx4 >> 10;
    const int idx = idx4 & 1023;
    const int lw = idx >> 4;
    const int lc4 = idx & 15;
    float4* obase = reinterpret_cast<float4*>(
        out + XF_OFF + ((size_t)(h0 + row) * HW + w0) * 64);
    obase[idx] = *reinterpret_cast<const float4*>(&ldsT[row][lw][lc4 * 4]);
  }
}

extern "C" void kernel_launch(void* const* d_in, const int* in_sizes, int n_in,
                              void* d_out, int out_size, void* d_ws, size_t ws_size,
                              hipStream_t stream) {
  (void)in_sizes; (void)n_in; (void)out_size; (void)ws_size;
  const float* in = reinterpret_cast<const float*>(d_in[0]);   // (1,64,512,512)
  const float* wgt = reinterpret_cast<const float*>(d_in[1]);  // (64,64,3,3)
  float* out = reinterpret_cast<float*>(d_out);                // wq | xf
  float* ws = reinterpret_cast<float*>(d_ws);

  (void)hipMemsetAsync(d_ws, 0, KSZ * sizeof(float), stream);  // act accum = 0
  k_pass1<<<dim3(2048 + 3), dim3(256), 0, stream>>>(in, wgt, ws);
  k_fused<<<dim3(1024), dim3(512), 0, stream>>>(in, wgt, ws, out);
}

// Round 6
// 53.297 us; speedup vs baseline: 1.9935x; 1.2807x over previous
//
#include <hip/hip_runtime.h>
#include <math.h>

#define HW 512
#define KSZ 576                     // C*K*K = 64*9
#define NCHUNK 16                   // 32-row chunks per channel
#define WS_PART 0                   // KSZ*NCHUNK floats, layout [j][chunk]
#define WS_WMAX (KSZ * NCHUNK)      // 576 floats
#define XF_OFF (64 * KSZ)           // wq = 36864 elements, xf follows

// ---------------------------------------------------------------------------
// Kernel 1 (1024 + 3 blocks):
//  blocks 0..1023: per-(channel, 32-row chunk) maxima of |input| for the 9
//  (kh,kw) validity regions -> ws[WS_PART + j*NCHUNK + chunk] (plain stores,
//  every slot written -> no init needed, deterministic).
//  blocks 1024..1026: wmax[j] = max_co |wgt[co,j]|.
// ---------------------------------------------------------------------------
__global__ __launch_bounds__(256) void k_pass1(const float* __restrict__ in,
                                               const float* __restrict__ wgt,
                                               float* __restrict__ ws) {
  const int t = threadIdx.x;
  if (blockIdx.x >= 1024) {                  // wmax tail blocks
    const int j = (blockIdx.x - 1024) * 256 + t;
    if (j < KSZ) {
      float wm = 0.f;
#pragma unroll 16
      for (int co = 0; co < 64; ++co) wm = fmaxf(wm, fabsf(wgt[co * KSZ + j]));
      ws[WS_WMAX + j] = wm;
    }
    return;
  }
  const int c = blockIdx.x >> 4;
  const int chunk = blockIdx.x & 15;
  const float4* base = reinterpret_cast<const float4*>(
      in + (size_t)c * HW * HW + (size_t)(chunk << 5) * HW);

  float4 v[16];
#pragma unroll
  for (int k = 0; k < 16; ++k) v[k] = base[k * 256 + t];  // 16 loads in flight

  const int col4 = t & 127;     // w-border lanes are static per thread
  const int tb = t >> 7;
  float aAll = 0.f, aNo0 = 0.f, aNoL = 0.f;   // all rows of chunk
  float bAll = 0.f, bNo0 = 0.f, bNoL = 0.f;   // excluding chunk's border row
#pragma unroll
  for (int k = 0; k < 16; ++k) {
    const float e0 = fabsf(v[k].x), e1 = fabsf(v[k].y),
                e2 = fabsf(v[k].z), e3 = fabsf(v[k].w);
    const float m4 = fmaxf(fmaxf(e0, e1), fmaxf(e2, e3));
    const float vNo0 = (col4 == 0)   ? fmaxf(fmaxf(e1, e2), e3) : m4; // excl w=0
    const float vNoL = (col4 == 127) ? fmaxf(fmaxf(e0, e1), e2) : m4; // excl w=511
    aAll = fmaxf(aAll, m4); aNo0 = fmaxf(aNo0, vNo0); aNoL = fmaxf(aNoL, vNoL);
    const int lrow = 2 * k + tb;
    const bool keep = !((chunk == 0 && lrow == 0) || (chunk == 15 && lrow == 31));
    if (keep) {
      bAll = fmaxf(bAll, m4); bNo0 = fmaxf(bNo0, vNo0); bNoL = fmaxf(bNoL, vNoL);
    }
  }
#pragma unroll
  for (int m = 32; m >= 1; m >>= 1) {
    aAll = fmaxf(aAll, __shfl_xor(aAll, m));
    aNo0 = fmaxf(aNo0, __shfl_xor(aNo0, m));
    aNoL = fmaxf(aNoL, __shfl_xor(aNoL, m));
    bAll = fmaxf(bAll, __shfl_xor(bAll, m));
    bNo0 = fmaxf(bNo0, __shfl_xor(bNo0, m));
    bNoL = fmaxf(bNoL, __shfl_xor(bNoL, m));
  }
  __shared__ float red[4][6];
  if ((t & 63) == 0) {
    const int wv = t >> 6;
    red[wv][0] = aAll; red[wv][1] = aNo0; red[wv][2] = aNoL;
    red[wv][3] = bAll; red[wv][4] = bNo0; red[wv][5] = bNoL;
  }
  __syncthreads();
  if (t == 0) {
    float r[6];
#pragma unroll
    for (int i = 0; i < 6; ++i)
      r[i] = fmaxf(fmaxf(red[0][i], red[1][i]), fmaxf(red[2][i], red[3][i]));
    // kw mapping: kw=0 -> w<=510 (NoL), kw=1 -> All, kw=2 -> w>=1 (No0)
    const float Aw[3] = {r[2], r[0], r[1]};
    const float Bw[3] = {r[5], r[3], r[4]};
    float* part = ws + WS_PART;
#pragma unroll
    for (int b = 0; b < 3; ++b) {
      const int j0 = c * 9 + 0 * 3 + b, j1 = c * 9 + 3 + b, j2 = c * 9 + 6 + b;
      part[j0 * NCHUNK + chunk] = (chunk == 15) ? Bw[b] : Aw[b];  // kh=0: h<=510
      part[j1 * NCHUNK + chunk] = Aw[b];                          // kh=1
      part[j2 * NCHUNK + chunk] = (chunk == 0) ? Bw[b] : Aw[b];   // kh=2: h>=1
    }
  }
}

// ---------------------------------------------------------------------------
// Kernel 2 (2048 blocks x 256 thr): issue main-tile loads, then (overlapped)
// reduce partials -> act, derive scale/sx/sw/rq (identical FP ops per block
// -> deterministic). Blocks 0..63 write wq row co=blockIdx. Then 2-row x
// 64w x 64c quantize tile, interior no-clamp fast path, LDS transpose.
// LDS ~37 KB -> 4 blocks/CU.
// ---------------------------------------------------------------------------
__global__ __launch_bounds__(256) void k_fused(const float* __restrict__ in,
                                               const float* __restrict__ wgt,
                                               const float* __restrict__ ws,
                                               float* __restrict__ out) {
  __shared__ float rq_s[KSZ];
  __shared__ float ldsT[2][64][68];   // [row][w_local][c], pad 68 (2-way = free)
  __shared__ float red[4][2];
  __shared__ float s_sx, s_sw;
  const int t = threadIdx.x;
  const int h0 = (blockIdx.x >> 3) << 1;   // 256 h-blocks * 2 rows
  const int w0 = (blockIdx.x & 7) << 6;
  const int c = t >> 2;                    // 4 threads per channel
  const int fi = t & 3;

  // ---- issue main input loads first; prologue hides under them ----
  const float4* ibase = reinterpret_cast<const float4*>(
      in + (size_t)c * HW * HW + (size_t)h0 * HW + w0);
  float4 v[8];
#pragma unroll
  for (int r = 0; r < 2; ++r)
#pragma unroll
    for (int k = 0; k < 4; ++k) v[r * 4 + k] = ibase[r * 128 + fi + 4 * k];

  // ---- scales (redundant per block, L2-hit) ----
  float scale_r[3];
  float rxm = 0.f, rwm = 0.f;
#pragma unroll
  for (int rep = 0; rep < 3; ++rep) {
    const int j = t + rep * 256;
    if (j < KSZ) {
      const float4* pp = reinterpret_cast<const float4*>(ws + WS_PART + j * NCHUNK);
      const float4 p0 = pp[0], p1 = pp[1], p2 = pp[2], p3 = pp[3];
      float act = fmaxf(fmaxf(fmaxf(p0.x, p0.y), fmaxf(p0.z, p0.w)),
                        fmaxf(fmaxf(p1.x, p1.y), fmaxf(p1.z, p1.w)));
      act = fmaxf(act, fmaxf(fmaxf(fmaxf(p2.x, p2.y), fmaxf(p2.z, p2.w)),
                             fmaxf(fmaxf(p3.x, p3.y), fmaxf(p3.z, p3.w))));
      const float wm = ws[WS_WMAX + j];
      float scale = sqrtf(act) / sqrtf(wm);   // alpha = 0.5
      if (scale == 0.f) scale = 1.f;
      scale_r[rep] = scale;
      rxm = fmaxf(rxm, act / scale);
      rwm = fmaxf(rwm, wm * scale);
    }
  }
#pragma unroll
  for (int m = 32; m >= 1; m >>= 1) {
    rxm = fmaxf(rxm, __shfl_xor(rxm, m));
    rwm = fmaxf(rwm, __shfl_xor(rwm, m));
  }
  if ((t & 63) == 0) { red[t >> 6][0] = rxm; red[t >> 6][1] = rwm; }
  __syncthreads();
  if (t == 0) {
    float mx = red[0][0], mw = red[0][1];
    for (int i = 1; i < 4; ++i) { mx = fmaxf(mx, red[i][0]); mw = fmaxf(mw, red[i][1]); }
    s_sx = (mx > 0.f) ? (mx / 127.f) : 1.f;
    s_sw = (mw > 0.f) ? (mw / 127.f) : 1.f;
  }
  __syncthreads();
  const float sx = s_sx, sw = s_sw;
#pragma unroll
  for (int rep = 0; rep < 3; ++rep) {
    const int j = t + rep * 256;
    if (j < KSZ) rq_s[j] = 1.f / (scale_r[rep] * sx);
  }
  __syncthreads();

  // ---- wq epilogue: blocks 0..63 each write one cout row ----
  if (blockIdx.x < 64) {
    const int co = blockIdx.x;
#pragma unroll
    for (int rep = 0; rep < 3; ++rep) {
      const int j = t + rep * 256;
      if (j < KSZ) {
        const int cc = j / 9;
        const int r = j - cc * 9;
        float u = (wgt[co * KSZ + j] * scale_r[rep]) / sw;
        u = fminf(fmaxf(u, -127.f), 127.f);
        out[co * KSZ + r * 64 + cc] = rintf(u) * sw;
      }
    }
  }

  // ---- main tile ----
  float rq[9];
#pragma unroll
  for (int jq = 0; jq < 9; ++jq) rq[jq] = rq_s[c * 9 + jq];

#pragma unroll
  for (int r = 0; r < 2; ++r) {
    const int h = h0 + r;
    const bool hb = (h == 0) || (h == 511);
#pragma unroll
    for (int k = 0; k < 4; ++k) {
      const float4 v4 = v[r * 4 + k];
      const int f4 = fi + 4 * k;
      const float vv[4] = {v4.x, v4.y, v4.z, v4.w};
#pragma unroll
      for (int i = 0; i < 4; ++i) {
        const int wl = f4 * 4 + i;
        const int w = w0 + wl;
        const float x = vv[i];
        float qs = 0.f;
#pragma unroll
        for (int jj = 0; jj < 9; ++jj) qs += rintf(x * rq[jj]);  // exact int sum
        if (hb || (w == 0) || (w == 511)) {                      // rare fix-up
          const bool hok0 = (h <= 510), hok2 = (h >= 1);
          const bool wok0 = (w <= 510), wok2 = (w >= 1);
          const bool ok[9] = {hok0 && wok0, hok0, hok0 && wok2,
                              wok0,         true, wok2,
                              hok2 && wok0, hok2, hok2 && wok2};
          qs = 0.f;
#pragma unroll
          for (int jj = 0; jj < 9; ++jj) {
            const float u = fminf(fmaxf(x * rq[jj], -127.f), 127.f);
            qs += ok[jj] ? rintf(u) : 0.f;
          }
        }
        ldsT[r][wl][c] = qs * sx;
      }
    }
  }
  __syncthreads();

#pragma unroll
  for (int k = 0; k < 8; ++k) {
    const int idx4 = k * 256 + t;
    const int row = idx4 >> 10;          // 1024 float4 per row
    const int idx = idx4 & 1023;
    const int lw = idx >> 4;
    const int lc4 = idx & 15;
    float4* obase = reinterpret_cast<float4*>(
        out + XF_OFF + ((size_t)(h0 + row) * HW + w0) * 64);
    obase[idx] = *reinterpret_cast<const float4*>(&ldsT[row][lw][lc4 * 4]);
  }
}

extern "C" void kernel_launch(void* const* d_in, const int* in_sizes, int n_in,
                              void* d_out, int out_size, void* d_ws, size_t ws_size,
                              hipStream_t stream) {
  (void)in_sizes; (void)n_in; (void)out_size; (void)ws_size;
  const float* in = reinterpret_cast<const float*>(d_in[0]);   // (1,64,512,512)
  const float* wgt = reinterpret_cast<const float*>(d_in[1]);  // (64,64,3,3)
  float* out = reinterpret_cast<float*>(d_out);                // wq | xf
  float* ws = reinterpret_cast<float*>(d_ws);

  k_pass1<<<dim3(1024 + 3), dim3(256), 0, stream>>>(in, wgt, ws);
  k_fused<<<dim3(2048), dim3(256), 0, stream>>>(in, wgt, ws, out);
}